// Round 3
// baseline (474.436 us; speedup 1.0000x reference)
//
#include <hip/hip_runtime.h>

// SpatiotemporalAttention: B=1, FRAMES=16, P=64, C=512, window (2,8,8)=L128,
// NH=8, HD=64, NWIN=512. All GEMMs bf16 MFMA 16x16x32, fp32 accumulate.
//
// R5: (1) oproj ported to the same 8-phase 256^2 schedule as qkv_gemm8
//     (grid 512 = 2 rounds, fp32 + bias + window-merge epilogue).
//     (2) attn restructured: Q loaded directly into MFMA fragments from
//     global (no LDS staging), P overlays the K tile in two 64-col halves
//     (P's PV rows are wave-private -> only one barrier needed), LDS
//     48KB -> 32KB so 4-5 blocks/CU instead of 3.  qkv_gemm8 untouched.
//
// Workspace layout (bytes):
//   [0,          67108864)  xbf  : window-ordered x, bf16 [65536][512]; reused as O after attention
//   [67108864,  134217728)  Q    : [512][8][128][64] bf16 (pre-scaled by 0.125)
//   [134217728, 201326592)  K    : [512][8][128][64] bf16
//   [201326592, 268435456)  Vt   : [512][8][64][128] bf16 (transposed)
//   [268435456, 270532608)  Wb   : Wq,Wk,Wv,Wo bf16, 512KB each

typedef __bf16 bf16x8 __attribute__((ext_vector_type(8)));
typedef float  f32x4  __attribute__((ext_vector_type(4)));

__device__ __forceinline__ unsigned short f2bf(float f) {
    unsigned int u = __float_as_uint(f);
    u += 0x7FFFu + ((u >> 16) & 1u);   // round-to-nearest-even
    return (unsigned short)(u >> 16);
}
__device__ __forceinline__ unsigned int pack2(float lo, float hi) {
    return (unsigned int)f2bf(lo) | ((unsigned int)f2bf(hi) << 16);
}
__device__ __forceinline__ void glds16(const void* g, void* l) {
    __builtin_amdgcn_global_load_lds(
        (const __attribute__((address_space(1))) unsigned int*)g,
        (__attribute__((address_space(3))) unsigned int*)l, 16, 0, 0);
}

// ---------------- kernel 0: gather x into window order, fp32 -> bf16 ----------------
__global__ __launch_bounds__(256) void gather_cvt(const float* __restrict__ x,
                                                  unsigned short* __restrict__ xbf) {
    int tid = blockIdx.x * 256 + threadIdx.x;   // one thread per 8 elements
    int r = tid >> 6;                            // window-ordered row 0..65535
    int c = (tid & 63) << 3;                     // col start (8 floats)
    int w = r >> 7, l = r & 127;
    int wt = w >> 6, wy = (w >> 3) & 7, wx = w & 7;
    int lt = l >> 6, ly = (l >> 3) & 7, lx = l & 7;
    size_t n = (size_t)(wt * 2 + lt) * 4096 + (size_t)(wy * 8 + ly) * 64 + (wx * 8 + lx);
    const float4* s = (const float4*)(x + n * 512 + c);
    float4 a = s[0], b = s[1];
    uint4 o;
    o.x = pack2(a.x, a.y); o.y = pack2(a.z, a.w);
    o.z = pack2(b.x, b.y); o.w = pack2(b.z, b.w);
    *(uint4*)(xbf + (size_t)r * 512 + c) = o;
}

// ---------------- kernel 1: weights fp32 -> bf16, all 4 in one launch ----------------
__global__ __launch_bounds__(256) void cvt_w4(const float* __restrict__ Wq,
                                              const float* __restrict__ Wk,
                                              const float* __restrict__ Wv,
                                              const float* __restrict__ Wo,
                                              unsigned short* __restrict__ d) {
    int b = blockIdx.x >> 7;                     // which weight
    int tid = (blockIdx.x & 127) * 256 + threadIdx.x;   // per 8 elements
    const float* s = (b == 0) ? Wq : (b == 1) ? Wk : (b == 2) ? Wv : Wo;
    const float4* sp = (const float4*)s + (size_t)tid * 2;
    float4 a = sp[0], bb = sp[1];
    uint4 o;
    o.x = pack2(a.x, a.y); o.y = pack2(a.z, a.w);
    o.z = pack2(bb.x, bb.y); o.w = pack2(bb.z, bb.w);
    ((uint4*)(d + (size_t)b * 262144))[tid] = o;
}

// ---------------- shared 8-phase 256^2 GEMM machinery ----------------
// LDS (128KB, dynamic): A halves [2 dbuf][2 kh][256 rows][32 cols] bf16 at 0,
//                       B halves same at +32768 elements.
// Swizzle: 16B chunk slot s in a row holds global k-chunk s ^ ((row>>1)&3)
// (applied on the global source address; glds writes LDS linearly).

#define STAGE_A(tt, kh) do {                                                   \
    const unsigned short* g_ = Ap + (size_t)(tt) * 64 + (kh) * 32 + gOff;      \
    unsigned short* l_ = smem + ((((tt) & 1) * 2 + (kh)) * 8192);              \
    glds16(g_, l_ + j * 8);                                                    \
    glds16(g_ + 65536, l_ + 4096 + j * 8);                                     \
  } while (0)

#define STAGE_B(tt, kh) do {                                                   \
    const unsigned short* g_ = Bp + (size_t)(tt) * 64 + (kh) * 32 + gOff;      \
    unsigned short* l_ = smem + 32768 + ((((tt) & 1) * 2 + (kh)) * 8192);      \
    glds16(g_, l_ + j * 8);                                                    \
    glds16(g_ + 65536, l_ + 4096 + j * 8);                                     \
  } while (0)

#define PH_READA(d, ks, mh)                                                    \
    _Pragma("unroll") for (int i_ = 0; i_ < 4; ++i_)                           \
      af[i_] = *(const bf16x8*)(smem + ((d) * 2 + (ks)) * 8192 +               \
                                (arow + (mh) * 64 + i_ * 16) * 32 + ech);

#define PH_READB(d, ks)                                                        \
    _Pragma("unroll") for (int n_ = 0; n_ < 4; ++n_)                           \
      bfr[n_] = *(const bf16x8*)(smem + 32768 + ((d) * 2 + (ks)) * 8192 +      \
                                 (brow + n_ * 16) * 32 + ech);

#define PH_MFMA(mh)                                                            \
    __builtin_amdgcn_s_barrier();                                              \
    asm volatile("s_waitcnt lgkmcnt(0)" ::: "memory");                         \
    __builtin_amdgcn_sched_barrier(0);                                         \
    __builtin_amdgcn_s_setprio(1);                                             \
    _Pragma("unroll") for (int n_ = 0; n_ < 4; ++n_)                           \
      _Pragma("unroll") for (int i_ = 0; i_ < 4; ++i_)                         \
        acc[(mh) * 4 + i_][n_] = __builtin_amdgcn_mfma_f32_16x16x32_bf16(      \
            af[i_], bfr[n_], acc[(mh) * 4 + i_][n_], 0, 0, 0);                 \
    __builtin_amdgcn_s_setprio(0);                                             \
    __builtin_amdgcn_s_barrier();

// K-loop body shared by both 256^2 GEMMs (8 K-tiles, K=512)
#define GEMM8_MAIN_LOOP                                                        \
    STAGE_A(0, 0); STAGE_B(0, 0); STAGE_A(0, 1); STAGE_B(0, 1);                \
    STAGE_A(1, 0); STAGE_B(1, 0);                                              \
    asm volatile("s_waitcnt vmcnt(4)" ::: "memory");                           \
    __builtin_amdgcn_s_barrier();                                              \
    _Pragma("unroll 2")                                                        \
    for (int t = 0; t < 8; ++t) {                                              \
        const int d = t & 1;                                                   \
        PH_READA(d, 0, 0); PH_READB(d, 0);                                     \
        if (t < 7) STAGE_A(t + 1, 1);                                          \
        PH_MFMA(0);                                                            \
        PH_READA(d, 0, 1);                                                     \
        if (t < 7) {                                                           \
            STAGE_B(t + 1, 1);                                                 \
            asm volatile("s_waitcnt vmcnt(4)" ::: "memory");                   \
        }                                                                      \
        PH_MFMA(1);                                                            \
        PH_READA(d, 1, 0); PH_READB(d, 1);                                     \
        if (t < 6) STAGE_A(t + 2, 0);                                          \
        PH_MFMA(0);                                                            \
        PH_READA(d, 1, 1);                                                     \
        if (t < 6) {                                                           \
            STAGE_B(t + 2, 0);                                                 \
            asm volatile("s_waitcnt vmcnt(4)" ::: "memory");                   \
        } else if (t == 6) {                                                   \
            asm volatile("s_waitcnt vmcnt(0)" ::: "memory");                   \
        }                                                                      \
        PH_MFMA(1);                                                            \
    }

// ---------------- kernel 2: fused QKV projection GEMM, 8-phase 256^2 ----------------
// C[65536][1536] = xbf @ [Wq|Wk|Wv rows]^T. Grid 1536 = 256 rowblks x 6 colblks,
// XCD-aware: the 6 colblks sharing an A-panel land on one XCD.
__global__ __launch_bounds__(512, 2) void qkv_gemm8(const unsigned short* __restrict__ xbf,
                                                    const unsigned short* __restrict__ wb,
                                                    unsigned short* __restrict__ Qb,
                                                    unsigned short* __restrict__ Kb,
                                                    unsigned short* __restrict__ Vb) {
    extern __shared__ unsigned short smem[];
    int id = blockIdx.x;
    int xcd = id & 7, rest = id >> 3;            // rest in [0,192)
    int rowblk = xcd * 32 + rest / 6;            // 256 row-blocks of 256 rows
    int colblk = rest % 6;                       // 6 col-blocks of 256 cols

    const unsigned short* Ap = xbf + (size_t)rowblk * 131072;
    const unsigned short* Bp = wb + (size_t)colblk * 131072;

    int j = threadIdx.x;                         // 0..511
    int lane = j & 63, wv = j >> 6;
    int wm = wv >> 2, wn = wv & 3;               // 2M x 4N waves
    int quad = lane >> 4, lc = lane & 15;

    // staging: thread j owns chunks j and j+512 of each 16KB half-tile.
    // chunk c -> row c>>2, slot c&3 holds global k-chunk (c&3)^((c>>3)&3).
    int r0 = j >> 2;
    int dcol = (((j & 3) ^ ((j >> 3) & 3)) << 3);
    const size_t gOff = (size_t)r0 * 512 + dcol;

    // read side: frag row R (R%16==lc) at slot quad^((lc>>1)&3)
    int arow = wm * 128 + lc;
    int brow = wn * 64 + lc;
    int ech = (quad ^ ((lc >> 1) & 3)) << 3;     // element offset of 16B chunk

    f32x4 acc[8][4] = {};
    bf16x8 af[4], bfr[4];

    GEMM8_MAIN_LOOP

    // ---- epilogue: stage C through LDS, then coalesced wide stores ----
    // Each wave's 128x64 sub-tile is exactly one (window, head) of one proj.
    unsigned short* sc = smem + wv * 8192;       // 8192 elems = 16KB per wave
    int cb = colblk * 256 + wn * 64;
    int pj = cb >> 9;                            // 0=Q 1=K 2=V
    int h = (cb >> 6) & 7;
    int w2 = rowblk * 2 + wm;                    // window
    size_t ob = ((size_t)w2 * 8 + h) * 8192;

    if (pj == 2) {
        // V: transpose to [d][l] in LDS; 16 chunks/row, slot = k ^ (d&7)
        #pragma unroll
        for (int mi = 0; mi < 8; ++mi)
            #pragma unroll
            for (int n = 0; n < 4; ++n)
                #pragma unroll
                for (int rg = 0; rg < 4; ++rg) {
                    int l = mi * 16 + quad * 4 + rg;
                    int d2 = n * 16 + lc;
                    sc[d2 * 128 + (((l >> 3) ^ (d2 & 7)) << 3) + (l & 7)] =
                        f2bf(acc[mi][n][rg]);
                }
        asm volatile("s_waitcnt lgkmcnt(0)" ::: "memory");
        #pragma unroll
        for (int i = 0; i < 16; ++i) {
            int ci = i * 64 + lane;              // chunk of the [64][128] tile
            int d2 = ci >> 4, k = ci & 15;
            uint4 val = *(const uint4*)(sc + d2 * 128 + ((k ^ (d2 & 7)) << 3));
            *(uint4*)(Vb + ob + (size_t)ci * 8) = val;
        }
    } else {
        unsigned short* outp = pj ? Kb : Qb;
        float s = pj ? 1.0f : 0.125f;
        // Q/K: [l][d] in LDS; 8 chunks/row, slot = k ^ (l&7)
        #pragma unroll
        for (int mi = 0; mi < 8; ++mi)
            #pragma unroll
            for (int n = 0; n < 4; ++n)
                #pragma unroll
                for (int rg = 0; rg < 4; ++rg) {
                    int l = mi * 16 + quad * 4 + rg;
                    int d2 = n * 16 + lc;
                    sc[l * 64 + (((d2 >> 3) ^ (l & 7)) << 3) + (d2 & 7)] =
                        f2bf(acc[mi][n][rg] * s);
                }
        asm volatile("s_waitcnt lgkmcnt(0)" ::: "memory");
        #pragma unroll
        for (int i = 0; i < 16; ++i) {
            int ci = i * 64 + lane;              // chunk of the [128][64] tile
            int l = ci >> 3, k = ci & 7;
            uint4 val = *(const uint4*)(sc + l * 64 + ((k ^ (l & 7)) << 3));
            *(uint4*)(outp + ob + (size_t)ci * 8) = val;
        }
    }
}

// ---------------- kernel 3: per-(window,head) attention ----------------
// grid (8 heads, 512 windows), 256 threads (4 waves); wave wv owns rows 32wv..32wv+31.
// LDS 32KB: sV [64][128] + sKP [128][64] (K, then P in two 64-col halves).
// Q loaded directly into MFMA fragments from global (fragment-aligned 16B).
// P's PV A-operand rows are wave-private -> no barrier between P write and PV.
__global__ __launch_bounds__(256) void attn(const unsigned short* __restrict__ Qb,
                                            const unsigned short* __restrict__ Kb,
                                            const unsigned short* __restrict__ Vb,
                                            unsigned short* __restrict__ O) {
    int h = blockIdx.x, w = blockIdx.y;
    size_t base = ((size_t)w * 8 + h) * 8192;
    const unsigned short* q = Qb + base;
    const unsigned short* k = Kb + base;
    const unsigned short* v = Vb + base;   // Vt [64][128]

    __shared__ unsigned short smem[16384];           // 32768 bytes
    unsigned short* sV = smem;                       // [64][128] swizzled
    unsigned short* sKP = smem + 8192;               // [128][64]: K, then P halves

    int t = threadIdx.x, lane = t & 63, wv = t >> 6;
    int quad = lane >> 4, lc = lane & 15;
    int sw = lc & 7;

    #pragma unroll
    for (int i = 0; i < 4; i++) {
        int s = t + i * 256;
        int r = s >> 3;
        int cq = ((s & 7) ^ (r & 7)) * 8;            // K: 8 chunks/row
        glds16(k + (size_t)r * 64 + cq, sKP + s * 8);
        int rv = s >> 4;
        int cv = (((s & 15) ^ (rv & 7))) * 8;        // V: 16 chunks/row, swizzle low 3 bits
        glds16(v + (size_t)rv * 128 + cv, sV + s * 8);
    }

    // Q straight into fragments: af(mi,ks) = Q[wv*32+mi*16+lc][ks*32+quad*8 ..+7]
    bf16x8 aq[2][2];
    #pragma unroll
    for (int mi = 0; mi < 2; mi++)
        #pragma unroll
        for (int ks = 0; ks < 2; ks++)
            aq[mi][ks] = *(const bf16x8*)(q + (size_t)(wv * 32 + mi * 16 + lc) * 64 +
                                          ks * 32 + quad * 8);
    __syncthreads();

    // S = Q @ K^T  (Q pre-scaled by 1/8)
    f32x4 acc[2][8] = {};
    #pragma unroll
    for (int ks = 0; ks < 2; ks++) {
        int ch = ((quad + ks * 4) ^ sw) * 8;
        #pragma unroll
        for (int ni = 0; ni < 8; ni++) {
            bf16x8 bfr = *(const bf16x8*)(&sKP[(ni * 16 + lc) * 64 + ch]);
            #pragma unroll
            for (int mi = 0; mi < 2; mi++)
                acc[mi][ni] = __builtin_amdgcn_mfma_f32_16x16x32_bf16(aq[mi][ks], bfr, acc[mi][ni], 0, 0, 0);
        }
    }

    // softmax fully in registers: row (mi,rg) lives in one 16-lane quad group
    #pragma unroll
    for (int mi = 0; mi < 2; mi++)
        #pragma unroll
        for (int rg = 0; rg < 4; rg++) {
            float m = -1e30f;
            #pragma unroll
            for (int ni = 0; ni < 8; ni++) m = fmaxf(m, acc[mi][ni][rg]);
            #pragma unroll
            for (int off = 1; off < 16; off <<= 1) m = fmaxf(m, __shfl_xor(m, off, 64));
            float s = 0.f;
            #pragma unroll
            for (int ni = 0; ni < 8; ni++) {
                float e = __expf(acc[mi][ni][rg] - m);
                acc[mi][ni][rg] = e;
                s += e;
            }
            #pragma unroll
            for (int off = 1; off < 16; off <<= 1) s += __shfl_xor(s, off, 64);
            float inv = 1.0f / s;
            #pragma unroll
            for (int ni = 0; ni < 8; ni++) acc[mi][ni][rg] *= inv;
        }

    __syncthreads();   // all waves done with K before P overlays sKP

    // O = P @ V in two 64-col halves of P; P rows are wave-private.
    f32x4 oc[2][4] = {};
    #pragma unroll
    for (int half = 0; half < 2; half++) {
        #pragma unroll
        for (int mi = 0; mi < 2; mi++)
            #pragma unroll
            for (int ni2 = 0; ni2 < 4; ni2++) {
                int ni = half * 4 + ni2;
                #pragma unroll
                for (int rg = 0; rg < 4; rg++) {
                    int r = wv * 32 + mi * 16 + quad * 4 + rg;
                    int c = ni2 * 16 + lc;
                    sKP[r * 64 + (((c >> 3) ^ (r & 7)) << 3) + (c & 7)] = f2bf(acc[mi][ni][rg]);
                }
            }
        asm volatile("s_waitcnt lgkmcnt(0)" ::: "memory");
        __builtin_amdgcn_sched_barrier(0);
        #pragma unroll
        for (int ks2 = 0; ks2 < 2; ks2++) {
            int chp = ((quad + ks2 * 4) ^ sw) * 8;              // P half [128][64]
            int chv = (half * 8 + ((ks2 * 4 + quad) ^ sw)) * 8; // V chunk (global k)
            bf16x8 af[2];
            #pragma unroll
            for (int mi = 0; mi < 2; mi++)
                af[mi] = *(const bf16x8*)(&sKP[(wv * 32 + mi * 16 + lc) * 64 + chp]);
            #pragma unroll
            for (int ni = 0; ni < 4; ni++) {
                bf16x8 bfr = *(const bf16x8*)(&sV[(ni * 16 + lc) * 128 + chv]);
                #pragma unroll
                for (int mi = 0; mi < 2; mi++)
                    oc[mi][ni] = __builtin_amdgcn_mfma_f32_16x16x32_bf16(af[mi], bfr, oc[mi][ni], 0, 0, 0);
            }
        }
    }

    #pragma unroll
    for (int mi = 0; mi < 2; mi++)
        #pragma unroll
        for (int ni = 0; ni < 4; ni++)
            #pragma unroll
            for (int rg = 0; rg < 4; rg++) {
                int l = wv * 32 + mi * 16 + quad * 4 + rg;
                int d = ni * 16 + lc;
                O[((size_t)w * 128 + l) * 512 + h * 64 + d] = f2bf(oc[mi][ni][rg]);
            }
}

// ---------------- kernel 4: output projection, 8-phase 256^2 ----------------
// C[65536][512] = O @ Wo^T + bias, window-merged fp32 output.
// Grid 512 = 256 rowblks x 2 colblks; the 2 colblks sharing an A-panel land
// on one XCD (ids differ by 8).
__global__ __launch_bounds__(512, 2) void oproj_gemm8(const unsigned short* __restrict__ A,
                                                      const unsigned short* __restrict__ Bw,
                                                      const float* __restrict__ bo,
                                                      float* __restrict__ out) {
    extern __shared__ unsigned short smem[];
    int id = blockIdx.x;
    int xcd = id & 7, rest = id >> 3;            // rest in [0,64)
    int rowblk = xcd * 32 + (rest >> 1);         // 256 row-blocks of 256 rows
    int colblk = rest & 1;                       // 2 col-blocks of 256 cols

    const unsigned short* Ap = A + (size_t)rowblk * 131072;
    const unsigned short* Bp = Bw + (size_t)colblk * 131072;

    int j = threadIdx.x;
    int lane = j & 63, wv = j >> 6;
    int wm = wv >> 2, wn = wv & 3;
    int quad = lane >> 4, lc = lane & 15;

    int r0 = j >> 2;
    int dcol = (((j & 3) ^ ((j >> 3) & 3)) << 3);
    const size_t gOff = (size_t)r0 * 512 + dcol;

    int arow = wm * 128 + lc;
    int brow = wn * 64 + lc;
    int ech = (quad ^ ((lc >> 1) & 3)) << 3;

    f32x4 acc[8][4] = {};
    bf16x8 af[4], bfr[4];

    GEMM8_MAIN_LOOP

    // epilogue: fp32 + bias + window merge, direct stores
    int cbase = colblk * 256 + wn * 64;
    float bias[4];
    #pragma unroll
    for (int ni = 0; ni < 4; ni++)
        bias[ni] = bo[cbase + ni * 16 + lc];

    #pragma unroll
    for (int mi = 0; mi < 8; ++mi)
        #pragma unroll
        for (int rg = 0; rg < 4; ++rg) {
            int r = rowblk * 256 + wm * 128 + mi * 16 + quad * 4 + rg;
            int w = r >> 7, l = r & 127;
            int wt = w >> 6, wy = (w >> 3) & 7, wx = w & 7;
            int lt = l >> 6, ly = (l >> 3) & 7, lx = l & 7;
            size_t n = (size_t)(wt * 2 + lt) * 4096 + (size_t)(wy * 8 + ly) * 64 + (wx * 8 + lx);
            #pragma unroll
            for (int ni = 0; ni < 4; ni++)
                out[n * 512 + cbase + ni * 16 + lc] = acc[mi][ni][rg] + bias[ni];
        }
}

extern "C" void kernel_launch(void* const* d_in, const int* in_sizes, int n_in,
                              void* d_out, int out_size, void* d_ws, size_t ws_size,
                              hipStream_t stream) {
    const float* x  = (const float*)d_in[0];
    const float* Wq = (const float*)d_in[1];
    const float* Wk = (const float*)d_in[2];
    const float* Wv = (const float*)d_in[3];
    const float* Wo = (const float*)d_in[4];
    const float* bo = (const float*)d_in[5];
    float* out = (float*)d_out;

    char* ws = (char*)d_ws;
    unsigned short* xbf = (unsigned short*)(ws);                  // also O after attention
    unsigned short* Qb  = (unsigned short*)(ws + 67108864);
    unsigned short* Kb  = (unsigned short*)(ws + 134217728);
    unsigned short* Vb  = (unsigned short*)(ws + 201326592);
    unsigned short* Wqb = (unsigned short*)(ws + 268435456);      // Wq,Wk,Wv,Wo consecutive

    static bool attrset = false;
    if (!attrset) {
        (void)hipFuncSetAttribute(reinterpret_cast<const void*>(qkv_gemm8),
                                  hipFuncAttributeMaxDynamicSharedMemorySize, 131072);
        (void)hipFuncSetAttribute(reinterpret_cast<const void*>(oproj_gemm8),
                                  hipFuncAttributeMaxDynamicSharedMemorySize, 131072);
        attrset = true;
    }

    gather_cvt<<<16384, 256, 0, stream>>>(x, xbf);
    cvt_w4<<<512, 256, 0, stream>>>(Wq, Wk, Wv, Wo, Wqb);

    qkv_gemm8<<<1536, 512, 131072, stream>>>(xbf, Wqb, Qb, Kb, Vb);
    attn<<<dim3(8, 512), 256, 0, stream>>>(Qb, Kb, Vb, xbf);
    oproj_gemm8<<<512, 512, 131072, stream>>>(xbf, Wqb + 786432, bo, out);
}

// Round 4
// 418.725 us; speedup vs baseline: 1.1331x; 1.1331x over previous
//
#include <hip/hip_runtime.h>

// SpatiotemporalAttention: B=1, FRAMES=16, P=64, C=512, window (2,8,8)=L128,
// NH=8, HD=64, NWIN=512. All GEMMs bf16 MFMA 16x16x32, fp32 accumulate.
//
// R6: FUSED qkv projection + attention. One block per (window, head):
//     stages x rows + per-head Wq/Wk/Wv slices (40KB dbuf x2 = 80KB LDS,
//     2 blocks/CU), accumulates Q/K/V in registers (96 VGPR), writes them
//     to LDS in the same swizzled layouts the verified R4-epilogue/R5-attn
//     pair used, then runs the R5 attention body from LDS. Q/K/V never
//     touch HBM: kills 192MB writes + 192MB reads + one kernel launch.
//     O written to the (now free) Qb workspace region; xbf stays read-only
//     because concurrent blocks still read it as the A operand.
//     Grid decode id=(w&7)+64*(w>>3)+8*h: all 8 heads of a window on one
//     XCD back-to-back -> A panel read once from HBM, 7x from L2.
//
// Workspace layout (bytes):
//   [0,          67108864)  xbf  : window-ordered x, bf16 [65536][512]
//   [67108864,  134217728)  Ob   : attention output, bf16 [65536][512]
//   [268435456, 270532608)  Wb   : Wq,Wk,Wv,Wo bf16, 512KB each

typedef __bf16 bf16x8 __attribute__((ext_vector_type(8)));
typedef float  f32x4  __attribute__((ext_vector_type(4)));

__device__ __forceinline__ unsigned short f2bf(float f) {
    unsigned int u = __float_as_uint(f);
    u += 0x7FFFu + ((u >> 16) & 1u);   // round-to-nearest-even
    return (unsigned short)(u >> 16);
}
__device__ __forceinline__ unsigned int pack2(float lo, float hi) {
    return (unsigned int)f2bf(lo) | ((unsigned int)f2bf(hi) << 16);
}
__device__ __forceinline__ void glds16(const void* g, void* l) {
    __builtin_amdgcn_global_load_lds(
        (const __attribute__((address_space(1))) unsigned int*)g,
        (__attribute__((address_space(3))) unsigned int*)l, 16, 0, 0);
}

// ---------------- kernel 0: gather x into window order, fp32 -> bf16 ----------------
__global__ __launch_bounds__(256) void gather_cvt(const float* __restrict__ x,
                                                  unsigned short* __restrict__ xbf) {
    int tid = blockIdx.x * 256 + threadIdx.x;   // one thread per 8 elements
    int r = tid >> 6;                            // window-ordered row 0..65535
    int c = (tid & 63) << 3;                     // col start (8 floats)
    int w = r >> 7, l = r & 127;
    int wt = w >> 6, wy = (w >> 3) & 7, wx = w & 7;
    int lt = l >> 6, ly = (l >> 3) & 7, lx = l & 7;
    size_t n = (size_t)(wt * 2 + lt) * 4096 + (size_t)(wy * 8 + ly) * 64 + (wx * 8 + lx);
    const float4* s = (const float4*)(x + n * 512 + c);
    float4 a = s[0], b = s[1];
    uint4 o;
    o.x = pack2(a.x, a.y); o.y = pack2(a.z, a.w);
    o.z = pack2(b.x, b.y); o.w = pack2(b.z, b.w);
    *(uint4*)(xbf + (size_t)r * 512 + c) = o;
}

// ---------------- kernel 1: weights fp32 -> bf16, all 4 in one launch ----------------
__global__ __launch_bounds__(256) void cvt_w4(const float* __restrict__ Wq,
                                              const float* __restrict__ Wk,
                                              const float* __restrict__ Wv,
                                              const float* __restrict__ Wo,
                                              unsigned short* __restrict__ d) {
    int b = blockIdx.x >> 7;                     // which weight
    int tid = (blockIdx.x & 127) * 256 + threadIdx.x;   // per 8 elements
    const float* s = (b == 0) ? Wq : (b == 1) ? Wk : (b == 2) ? Wv : Wo;
    const float4* sp = (const float4*)s + (size_t)tid * 2;
    float4 a = sp[0], bb = sp[1];
    uint4 o;
    o.x = pack2(a.x, a.y); o.y = pack2(a.z, a.w);
    o.z = pack2(bb.x, bb.y); o.w = pack2(bb.z, bb.w);
    ((uint4*)(d + (size_t)b * 262144))[tid] = o;
}

// ---------------- kernel 2: FUSED per-(window,head) QKV projection + attention ------
// grid 4096, 256 threads (4 waves). LDS 80KB dynamic:
//   projection phase: dbuf b at b*20480 elems: A[128][64] at 0 (8192 elems),
//                     W slice pj at 8192+pj*4096 ([64][64] each), all 8-chunk
//                     rows with 16B-chunk slot = chunk ^ (row&7).
//   attention phase:  sQ [0,8192), sK [8192,16384), sV [16384,24576);
//                     P overlays sK in two 64-col halves.
#define FSTAGE(tt) do {                                                        \
    unsigned short* sb_ = smem + ((tt) & 1) * 20480;                           \
    int k0_ = (tt) * 64;                                                       \
    _Pragma("unroll") for (int i_ = 0; i_ < 4; ++i_) {                         \
        int s_ = jj + i_ * 256, r_ = s_ >> 3;                                  \
        int cq_ = ((s_ & 7) ^ (r_ & 7)) * 8;                                   \
        glds16(Aw + (size_t)r_ * 512 + k0_ + cq_, sb_ + s_ * 8);               \
    }                                                                          \
    _Pragma("unroll") for (int p_ = 0; p_ < 3; ++p_)                           \
      _Pragma("unroll") for (int i_ = 0; i_ < 2; ++i_) {                       \
        int s_ = jj + i_ * 256, r_ = s_ >> 3;                                  \
        int cq_ = ((s_ & 7) ^ (r_ & 7)) * 8;                                   \
        glds16(Wp + (size_t)p_ * 262144 + (size_t)r_ * 512 + k0_ + cq_,        \
               sb_ + 8192 + p_ * 4096 + s_ * 8);                               \
    }                                                                          \
  } while (0)

__global__ __launch_bounds__(256, 2) void qkv_attn(const unsigned short* __restrict__ xbf,
                                                   const unsigned short* __restrict__ wb,
                                                   unsigned short* __restrict__ O) {
    extern __shared__ unsigned short smem[];
    int id = blockIdx.x;
    int w = (id & 7) + ((id >> 6) << 3);         // same XCD for all 8 heads of w
    int h = (id >> 3) & 7;
    const unsigned short* Aw = xbf + (size_t)w * 65536;      // [128][512]
    const unsigned short* Wp = wb + (size_t)h * 64 * 512;    // rows h*64.. of Wq

    int jj = threadIdx.x, lane = jj & 63, wv = jj >> 6;
    int quad = lane >> 4, lc = lane & 15, sw = lc & 7;

    // ---- projection: Q/K/V[128][64] = A[128][512] @ W[64][512]^T ----
    f32x4 acc[3][2][4] = {};
    FSTAGE(0);
    for (int t = 0; t < 8; ++t) {
        if (t < 7) {
            FSTAGE(t + 1);
            asm volatile("s_waitcnt vmcnt(10)" ::: "memory");  // tile t landed
        } else {
            asm volatile("s_waitcnt vmcnt(0)" ::: "memory");
        }
        __builtin_amdgcn_s_barrier();
        __builtin_amdgcn_sched_barrier(0);
        const unsigned short* sb = smem + (t & 1) * 20480;
        #pragma unroll
        for (int ks = 0; ks < 2; ++ks) {
            int ch = ((quad + ks * 4) ^ sw) * 8;
            bf16x8 af[2];
            #pragma unroll
            for (int mi = 0; mi < 2; ++mi)
                af[mi] = *(const bf16x8*)(sb + (wv * 32 + mi * 16 + lc) * 64 + ch);
            #pragma unroll
            for (int pj = 0; pj < 3; ++pj)
                #pragma unroll
                for (int ni = 0; ni < 4; ++ni) {
                    bf16x8 bfr = *(const bf16x8*)(sb + 8192 + pj * 4096 +
                                                  (ni * 16 + lc) * 64 + ch);
                    #pragma unroll
                    for (int mi = 0; mi < 2; ++mi)
                        acc[pj][mi][ni] = __builtin_amdgcn_mfma_f32_16x16x32_bf16(
                            af[mi], bfr, acc[pj][mi][ni], 0, 0, 0);
                }
        }
        __builtin_amdgcn_s_barrier();
        __builtin_amdgcn_sched_barrier(0);
    }

    // ---- Q/K/V -> LDS (same swizzled layouts the R4/R5 pair used) ----
    unsigned short* sQ = smem;                   // [128][64] swizzled
    unsigned short* sK = smem + 8192;            // [128][64] swizzled
    unsigned short* sV = smem + 16384;           // [64][128] swizzled (V^T)
    unsigned short* sP = sK;                     // P overlays K after QK^T
    #pragma unroll
    for (int mi = 0; mi < 2; ++mi)
        #pragma unroll
        for (int ni = 0; ni < 4; ++ni)
            #pragma unroll
            for (int rg = 0; rg < 4; ++rg) {
                int l = wv * 32 + mi * 16 + quad * 4 + rg;
                int d = ni * 16 + lc;
                int qs = l * 64 + (((d >> 3) ^ (l & 7)) << 3) + (d & 7);
                sQ[qs] = f2bf(acc[0][mi][ni][rg] * 0.125f);
                sK[qs] = f2bf(acc[1][mi][ni][rg]);
                sV[d * 128 + (((l >> 3) ^ (d & 7)) << 3) + (l & 7)] =
                    f2bf(acc[2][mi][ni][rg]);
            }
    __syncthreads();

    // ---- S = Q @ K^T (Q pre-scaled by 1/8) ----
    bf16x8 aq[2][2];
    #pragma unroll
    for (int mi = 0; mi < 2; ++mi)
        #pragma unroll
        for (int ks = 0; ks < 2; ++ks)
            aq[mi][ks] = *(const bf16x8*)(sQ + (wv * 32 + mi * 16 + lc) * 64 +
                                          (((quad + ks * 4) ^ sw) << 3));
    f32x4 sacc[2][8] = {};
    #pragma unroll
    for (int ks = 0; ks < 2; ++ks) {
        int ch = ((quad + ks * 4) ^ sw) * 8;
        #pragma unroll
        for (int ni = 0; ni < 8; ++ni) {
            bf16x8 bfr = *(const bf16x8*)(&sK[(ni * 16 + lc) * 64 + ch]);
            #pragma unroll
            for (int mi = 0; mi < 2; ++mi)
                sacc[mi][ni] = __builtin_amdgcn_mfma_f32_16x16x32_bf16(
                    aq[mi][ks], bfr, sacc[mi][ni], 0, 0, 0);
        }
    }

    // ---- softmax fully in registers: row (mi,rg) lives in one 16-lane quad group ----
    #pragma unroll
    for (int mi = 0; mi < 2; ++mi)
        #pragma unroll
        for (int rg = 0; rg < 4; ++rg) {
            float m = -1e30f;
            #pragma unroll
            for (int ni = 0; ni < 8; ++ni) m = fmaxf(m, sacc[mi][ni][rg]);
            #pragma unroll
            for (int off = 1; off < 16; off <<= 1) m = fmaxf(m, __shfl_xor(m, off, 64));
            float s = 0.f;
            #pragma unroll
            for (int ni = 0; ni < 8; ++ni) {
                float e = __expf(sacc[mi][ni][rg] - m);
                sacc[mi][ni][rg] = e;
                s += e;
            }
            #pragma unroll
            for (int off = 1; off < 16; off <<= 1) s += __shfl_xor(s, off, 64);
            float inv = 1.0f / s;
            #pragma unroll
            for (int ni = 0; ni < 8; ni++) sacc[mi][ni][rg] *= inv;
        }

    __syncthreads();   // all waves done reading sK before P overlays it

    // ---- O = P @ V in two 64-col halves of P; P rows are wave-private ----
    f32x4 oc[2][4] = {};
    #pragma unroll
    for (int half = 0; half < 2; ++half) {
        #pragma unroll
        for (int mi = 0; mi < 2; ++mi)
            #pragma unroll
            for (int ni2 = 0; ni2 < 4; ++ni2) {
                int ni = half * 4 + ni2;
                #pragma unroll
                for (int rg = 0; rg < 4; ++rg) {
                    int r = wv * 32 + mi * 16 + quad * 4 + rg;
                    int c = ni2 * 16 + lc;
                    sP[r * 64 + (((c >> 3) ^ (r & 7)) << 3) + (c & 7)] =
                        f2bf(sacc[mi][ni][rg]);
                }
            }
        asm volatile("s_waitcnt lgkmcnt(0)" ::: "memory");
        __builtin_amdgcn_sched_barrier(0);
        #pragma unroll
        for (int ks2 = 0; ks2 < 2; ++ks2) {
            int chp = ((quad + ks2 * 4) ^ sw) * 8;              // P half [128][64]
            int chv = (half * 8 + ((ks2 * 4 + quad) ^ sw)) * 8; // V chunk (global k)
            bf16x8 af[2];
            #pragma unroll
            for (int mi = 0; mi < 2; ++mi)
                af[mi] = *(const bf16x8*)(&sP[(wv * 32 + mi * 16 + lc) * 64 + chp]);
            #pragma unroll
            for (int ni = 0; ni < 4; ++ni) {
                bf16x8 bfr = *(const bf16x8*)(&sV[(ni * 16 + lc) * 128 + chv]);
                #pragma unroll
                for (int mi = 0; mi < 2; ++mi)
                    oc[mi][ni] = __builtin_amdgcn_mfma_f32_16x16x32_bf16(
                        af[mi], bfr, oc[mi][ni], 0, 0, 0);
            }
        }
    }

    #pragma unroll
    for (int mi = 0; mi < 2; ++mi)
        #pragma unroll
        for (int ni = 0; ni < 4; ++ni)
            #pragma unroll
            for (int rg = 0; rg < 4; ++rg) {
                int l = wv * 32 + mi * 16 + quad * 4 + rg;
                int d = ni * 16 + lc;
                O[((size_t)w * 128 + l) * 512 + h * 64 + d] = f2bf(oc[mi][ni][rg]);
            }
}

// ---------------- shared 8-phase 256^2 GEMM machinery (oproj) ----------------
#define STAGE_A(tt, kh) do {                                                   \
    const unsigned short* g_ = Ap + (size_t)(tt) * 64 + (kh) * 32 + gOff;      \
    unsigned short* l_ = smem + ((((tt) & 1) * 2 + (kh)) * 8192);              \
    glds16(g_, l_ + j * 8);                                                    \
    glds16(g_ + 65536, l_ + 4096 + j * 8);                                     \
  } while (0)

#define STAGE_B(tt, kh) do {                                                   \
    const unsigned short* g_ = Bp + (size_t)(tt) * 64 + (kh) * 32 + gOff;      \
    unsigned short* l_ = smem + 32768 + ((((tt) & 1) * 2 + (kh)) * 8192);      \
    glds16(g_, l_ + j * 8);                                                    \
    glds16(g_ + 65536, l_ + 4096 + j * 8);                                     \
  } while (0)

#define PH_READA(d, ks, mh)                                                    \
    _Pragma("unroll") for (int i_ = 0; i_ < 4; ++i_)                           \
      af[i_] = *(const bf16x8*)(smem + ((d) * 2 + (ks)) * 8192 +               \
                                (arow + (mh) * 64 + i_ * 16) * 32 + ech);

#define PH_READB(d, ks)                                                        \
    _Pragma("unroll") for (int n_ = 0; n_ < 4; ++n_)                           \
      bfr[n_] = *(const bf16x8*)(smem + 32768 + ((d) * 2 + (ks)) * 8192 +      \
                                 (brow + n_ * 16) * 32 + ech);

#define PH_MFMA(mh)                                                            \
    __builtin_amdgcn_s_barrier();                                              \
    asm volatile("s_waitcnt lgkmcnt(0)" ::: "memory");                         \
    __builtin_amdgcn_sched_barrier(0);                                         \
    __builtin_amdgcn_s_setprio(1);                                             \
    _Pragma("unroll") for (int n_ = 0; n_ < 4; ++n_)                           \
      _Pragma("unroll") for (int i_ = 0; i_ < 4; ++i_)                         \
        acc[(mh) * 4 + i_][n_] = __builtin_amdgcn_mfma_f32_16x16x32_bf16(      \
            af[i_], bfr[n_], acc[(mh) * 4 + i_][n_], 0, 0, 0);                 \
    __builtin_amdgcn_s_setprio(0);                                             \
    __builtin_amdgcn_s_barrier();

#define GEMM8_MAIN_LOOP                                                        \
    STAGE_A(0, 0); STAGE_B(0, 0); STAGE_A(0, 1); STAGE_B(0, 1);                \
    STAGE_A(1, 0); STAGE_B(1, 0);                                              \
    asm volatile("s_waitcnt vmcnt(4)" ::: "memory");                           \
    __builtin_amdgcn_s_barrier();                                              \
    _Pragma("unroll 2")                                                        \
    for (int t = 0; t < 8; ++t) {                                              \
        const int d = t & 1;                                                   \
        PH_READA(d, 0, 0); PH_READB(d, 0);                                     \
        if (t < 7) STAGE_A(t + 1, 1);                                          \
        PH_MFMA(0);                                                            \
        PH_READA(d, 0, 1);                                                     \
        if (t < 7) {                                                           \
            STAGE_B(t + 1, 1);                                                 \
            asm volatile("s_waitcnt vmcnt(4)" ::: "memory");                   \
        }                                                                      \
        PH_MFMA(1);                                                            \
        PH_READA(d, 1, 0); PH_READB(d, 1);                                     \
        if (t < 6) STAGE_A(t + 2, 0);                                          \
        PH_MFMA(0);                                                            \
        PH_READA(d, 1, 1);                                                     \
        if (t < 6) {                                                           \
            STAGE_B(t + 2, 0);                                                 \
            asm volatile("s_waitcnt vmcnt(4)" ::: "memory");                   \
        } else if (t == 6) {                                                   \
            asm volatile("s_waitcnt vmcnt(0)" ::: "memory");                   \
        }                                                                      \
        PH_MFMA(1);                                                            \
    }

// ---------------- kernel 3: output projection, 8-phase 256^2 ----------------
__global__ __launch_bounds__(512, 2) void oproj_gemm8(const unsigned short* __restrict__ A,
                                                      const unsigned short* __restrict__ Bw,
                                                      const float* __restrict__ bo,
                                                      float* __restrict__ out) {
    extern __shared__ unsigned short smem[];
    int id = blockIdx.x;
    int xcd = id & 7, rest = id >> 3;            // rest in [0,64)
    int rowblk = xcd * 32 + (rest >> 1);         // 256 row-blocks of 256 rows
    int colblk = rest & 1;                       // 2 col-blocks of 256 cols

    const unsigned short* Ap = A + (size_t)rowblk * 131072;
    const unsigned short* Bp = Bw + (size_t)colblk * 131072;

    int j = threadIdx.x;
    int lane = j & 63, wv = j >> 6;
    int wm = wv >> 2, wn = wv & 3;
    int quad = lane >> 4, lc = lane & 15;

    int r0 = j >> 2;
    int dcol = (((j & 3) ^ ((j >> 3) & 3)) << 3);
    const size_t gOff = (size_t)r0 * 512 + dcol;

    int arow = wm * 128 + lc;
    int brow = wn * 64 + lc;
    int ech = (quad ^ ((lc >> 1) & 3)) << 3;

    f32x4 acc[8][4] = {};
    bf16x8 af[4], bfr[4];

    GEMM8_MAIN_LOOP

    int cbase = colblk * 256 + wn * 64;
    float bias[4];
    #pragma unroll
    for (int ni = 0; ni < 4; ni++)
        bias[ni] = bo[cbase + ni * 16 + lc];

    #pragma unroll
    for (int mi = 0; mi < 8; ++mi)
        #pragma unroll
        for (int rg = 0; rg < 4; ++rg) {
            int r = rowblk * 256 + wm * 128 + mi * 16 + quad * 4 + rg;
            int w = r >> 7, l = r & 127;
            int wt = w >> 6, wy = (w >> 3) & 7, wx = w & 7;
            int lt = l >> 6, ly = (l >> 3) & 7, lx = l & 7;
            size_t n = (size_t)(wt * 2 + lt) * 4096 + (size_t)(wy * 8 + ly) * 64 + (wx * 8 + lx);
            #pragma unroll
            for (int ni = 0; ni < 4; ni++)
                out[n * 512 + cbase + ni * 16 + lc] = acc[mi][ni][rg] + bias[ni];
        }
}

extern "C" void kernel_launch(void* const* d_in, const int* in_sizes, int n_in,
                              void* d_out, int out_size, void* d_ws, size_t ws_size,
                              hipStream_t stream) {
    const float* x  = (const float*)d_in[0];
    const float* Wq = (const float*)d_in[1];
    const float* Wk = (const float*)d_in[2];
    const float* Wv = (const float*)d_in[3];
    const float* Wo = (const float*)d_in[4];
    const float* bo = (const float*)d_in[5];
    float* out = (float*)d_out;

    char* ws = (char*)d_ws;
    unsigned short* xbf = (unsigned short*)(ws);                  // A operand (read-only)
    unsigned short* Ob  = (unsigned short*)(ws + 67108864);       // attention output
    unsigned short* Wqb = (unsigned short*)(ws + 268435456);      // Wq,Wk,Wv,Wo consecutive

    static bool attrset = false;
    if (!attrset) {
        (void)hipFuncSetAttribute(reinterpret_cast<const void*>(qkv_attn),
                                  hipFuncAttributeMaxDynamicSharedMemorySize, 81920);
        (void)hipFuncSetAttribute(reinterpret_cast<const void*>(oproj_gemm8),
                                  hipFuncAttributeMaxDynamicSharedMemorySize, 131072);
        attrset = true;
    }

    gather_cvt<<<16384, 256, 0, stream>>>(x, xbf);
    cvt_w4<<<512, 256, 0, stream>>>(Wq, Wk, Wv, Wo, Wqb);

    qkv_attn<<<4096, 256, 81920, stream>>>(xbf, Wqb, Ob);
    oproj_gemm8<<<512, 512, 131072, stream>>>(Ob, Wqb + 786432, bo, out);
}